// Round 5
// baseline (110.854 us; speedup 1.0000x reference)
//
#include <hip/hip_runtime.h>
#include <math.h>

// Tropical (max-plus) matmul: y[b,o] = max_i (x[b,i] + W[o,i])
// x: [512,1024] f32, W: [1024,1024] f32 (K-innermost), y: [512,1024] f32.
//
// Round-5: latency-bound diagnosis (VALUBusy 20% @1 wave/SIMD r2; ~40us
// @2 waves/SIMD r4; time ~ 1/occupancy). This version targets 4 waves/SIMD:
//  - one wave per 64x64 tile, TM=TN=8, pk_add+max3 (1 inst/elem-k), as r4;
//  - NO register prefetch of next tile (that held 64 VGPRs through compute
//    and capped occupancy at 2 waves/SIMD; TLP now hides global latency);
//  - BK=16: LDS 8.25 KB/block -> 16 blocks/CU fits 132 KB;
//  - KS=32 split-K: 4096 blocks = 16/CU = 4 waves/SIMD;
//  - __launch_bounds__(64,4) pins VGPR <= 128 (est. usage ~110, no spill);
//  - wave-private LDS, zero barriers; chunk-swizzle p=c^(c>>2), 528 B rows:
//    fragment reads conflict-free (verified: chunk sets mod 8 are perms of
//    {0..7}), staging writes bank-balanced.
// Cost shift: reduce reads 64 MB (~11 us) -- net win if partial halves.

#define MDIM 512
#define NDIM 1024
#define KDIM 1024

#define TILE 64
#define BK 16
#define KPR (BK / 2)     // 8 k-pair rows per LDS tile
#define CH 33            // 32 data chunks (16 B) + 1 pad chunk per row
#define ROWF (CH * 4)    // 132 floats per kp-row (528 B)
#define NTHREADS 64

typedef float v2f __attribute__((ext_vector_type(2)));

__device__ __forceinline__ int swz(int c) { return c ^ (c >> 2); }

__global__ __launch_bounds__(NTHREADS, 4)
void tropical_partial(const float* __restrict__ x, const float* __restrict__ W,
                      float* __restrict__ ws, int KC) {
    __shared__ float As[KPR * ROWF];   // 4224 B
    __shared__ float Bs[KPR * ROWF];   // 4224 B

    const int tiles_n = NDIM / TILE;                // 16
    const int tm0 = (blockIdx.x / tiles_n) * TILE;
    const int tn0 = (blockIdx.x % tiles_n) * TILE;
    const int k0  = blockIdx.y * KC;

    const int l  = threadIdx.x;        // 0..63 (one wave)
    // staging map: q = k-chunk (4 floats), r0 = row base (16 row-groups)
    const int q  = l & 3;              // k-chunk 0..3
    const int r0 = l >> 2;             // 0..15; rows r0 + 16j, j=0..3
    // compute map
    const int tx = l & 7;              // n-direction
    const int ty = l >> 3;             // m-direction

    float acc[8][8];
#pragma unroll
    for (int i = 0; i < 8; ++i)
#pragma unroll
        for (int j = 0; j < 8; ++j) acc[i][j] = -INFINITY;

    const float* xb = x + (size_t)tm0 * KDIM + k0 + 4 * q;
    const float* wb = W + (size_t)tn0 * KDIM + k0 + 4 * q;

    const int nt = KC / BK;
    for (int t = 0; t < nt; ++t) {
        // stage tile t: 4+4 global float4 loads -> pair-interleaved LDS.
        // (wave-private LDS: program order suffices, no barrier.)
        const float* xt = xb + t * BK;
        const float* wt = wb + t * BK;
#pragma unroll
        for (int j = 0; j < 4; ++j) {
            const int ms  = r0 + 16 * j;                   // row within tile
            const int col = swz(ms >> 1) * 4 + (ms & 1) * 2;
            const float4 av = *(const float4*)(xt + (size_t)ms * KDIM);
            const float4 bv = *(const float4*)(wt + (size_t)ms * KDIM);
            v2f lo, hi;
            lo.x = av.x; lo.y = av.y;  hi.x = av.z; hi.y = av.w;
            *(v2f*)&As[(2 * q) * ROWF + col]     = lo;     // k-pair (4q,4q+1)
            *(v2f*)&As[(2 * q + 1) * ROWF + col] = hi;     // k-pair (4q+2,4q+3)
            lo.x = bv.x; lo.y = bv.y;  hi.x = bv.z; hi.y = bv.w;
            *(v2f*)&Bs[(2 * q) * ROWF + col]     = lo;
            *(v2f*)&Bs[(2 * q + 1) * ROWF + col] = hi;
        }
        // compute tile t: per kp-row, 4+4 conflict-free ds_read_b128,
        // then 64x (v_pk_add_f32 + v_max3_f32).
#pragma unroll
        for (int kp = 0; kp < KPR; ++kp) {
            const float* ra = As + kp * ROWF;
            const float* rb = Bs + kp * ROWF;
            float4 af[4], bf[4];
#pragma unroll
            for (int qq = 0; qq < 4; ++qq) {
                af[qq] = *(const float4*)(ra + ((4 * ty + qq) ^ ty) * 4);
                bf[qq] = *(const float4*)(rb + ((4 * tx + qq) ^ tx) * 4);
            }
            v2f am[8], bn[8];
#pragma unroll
            for (int qq = 0; qq < 4; ++qq) {
                am[2 * qq].x     = af[qq].x; am[2 * qq].y     = af[qq].y;
                am[2 * qq + 1].x = af[qq].z; am[2 * qq + 1].y = af[qq].w;
                bn[2 * qq].x     = bf[qq].x; bn[2 * qq].y     = bf[qq].y;
                bn[2 * qq + 1].x = bf[qq].z; bn[2 * qq + 1].y = bf[qq].w;
            }
#pragma unroll
            for (int i = 0; i < 8; ++i)
#pragma unroll
                for (int j = 0; j < 8; ++j) {
                    const v2f s = am[i] + bn[j];                    // v_pk_add_f32
                    acc[i][j] = fmaxf(fmaxf(acc[i][j], s.x), s.y);  // v_max3_f32
                }
        }
    }

    // epilogue: lane owns rows tm0+8ty+i, cols tn0+8tx..+7
    float* wsl = ws + (size_t)blockIdx.y * (MDIM * NDIM);
#pragma unroll
    for (int i = 0; i < 8; ++i) {
        float* r = &wsl[(size_t)(tm0 + 8 * ty + i) * NDIM + tn0 + 8 * tx];
        *(float4*)(r)     = make_float4(acc[i][0], acc[i][1], acc[i][2], acc[i][3]);
        *(float4*)(r + 4) = make_float4(acc[i][4], acc[i][5], acc[i][6], acc[i][7]);
    }
}

__global__ __launch_bounds__(256)
void tropical_reduce(const float* __restrict__ ws, float* __restrict__ out, int KS) {
    const int i = blockIdx.x * 256 + threadIdx.x;        // float4 index (exact grid)
    const int stride = MDIM * NDIM / 4;
    const float4* w4 = (const float4*)ws;
    float4 m = w4[i];
#pragma unroll 4
    for (int s = 1; s < KS; ++s) {
        const float4 v = w4[(size_t)s * stride + i];
        m.x = fmaxf(m.x, v.x); m.y = fmaxf(m.y, v.y);
        m.z = fmaxf(m.z, v.z); m.w = fmaxf(m.w, v.w);
    }
    ((float4*)out)[i] = m;
}

extern "C" void kernel_launch(void* const* d_in, const int* in_sizes, int n_in,
                              void* d_out, int out_size, void* d_ws, size_t ws_size,
                              hipStream_t stream) {
    const float* x = (const float*)d_in[0];
    const float* W = (const float*)d_in[1];
    float* out = (float*)d_out;
    float* ws  = (float*)d_ws;

    const size_t slice = (size_t)MDIM * NDIM * sizeof(float);  // 2 MB per K-slice
    int KS = 32;                                   // 4096 blocks = 16/CU = 4 w/SIMD
    while (KS > 1 && (size_t)KS * slice > ws_size) KS >>= 1;

    const int ntiles = (MDIM / TILE) * (NDIM / TILE);  // 128

    if (slice > ws_size) {
        // tiny-workspace fallback: single slice straight into out, no reduce
        tropical_partial<<<dim3(ntiles, 1), NTHREADS, 0, stream>>>(x, W, out, KDIM);
        return;
    }

    const int KC = KDIM / KS;
    tropical_partial<<<dim3(ntiles, KS), NTHREADS, 0, stream>>>(x, W, ws, KC);

    const int nvec4 = MDIM * NDIM / 4;                 // 131072
    tropical_reduce<<<nvec4 / 256, 256, 0, stream>>>(ws, out, KS);
}